// Round 16
// baseline (418.429 us; speedup 1.0000x reference)
//
#include <hip/hip_runtime.h>
#include <hip/hip_bf16.h>
#include <math.h>

#define DIM   384
#define HEADS 12
#define HD    32
#define WIN   7
#define NPIX  49
#define IMG   56
#define NPF   3136
#define NWIN  1024

typedef __attribute__((ext_vector_type(8))) short short8;
typedef __attribute__((ext_vector_type(4))) float f32x4;
typedef __attribute__((ext_vector_type(4))) float f4;
typedef __attribute__((ext_vector_type(4))) unsigned short us4;
typedef __attribute__((ext_vector_type(8))) unsigned short us8;
#define MFMA __builtin_amdgcn_mfma_f32_16x16x32_bf16

__device__ inline ushort tob(float f) {
  unsigned u; __builtin_memcpy(&u, &f, 4);
  u += 0x7fffu + ((u >> 16) & 1u);
  return (ushort)(u >> 16);
}

// ---------------- bias table ----------------
__global__ void k_bias(const float* __restrict__ cpb, float* __restrict__ bias) {
  int idx = blockIdx.x * 256 + threadIdx.x;
  if (idx >= HEADS * NPIX * NPIX) return;
  int m = idx % NPIX;
  int n = (idx / NPIX) % NPIX;
  int h = idx / (NPIX * NPIX);
  int sy = (n / WIN - m / WIN) + (WIN - 1);
  int sx = (n % WIN - m % WIN) + (WIN - 1);
  const double inv_log_beta = 1.0 / log(1.3);
  double fy = (sy == 0 ? 0.0 : log1p((double)sy) * inv_log_beta) + 6.0;
  double fx = (sx == 0 ? 0.0 : log1p((double)sx) * inv_log_beta) + 6.0;
  fy = fmin(12.0, fmax(0.0, fy));
  fx = fmin(12.0, fmax(0.0, fx));
  int ridx = (int)(fy * 13.0 + fx);
  bias[idx] = cpb[ridx * HEADS + h];
}

__global__ void k_rmap(int* __restrict__ rmap) {
  int p = blockIdx.x * 256 + threadIdx.x;
  if (p < NPF) {
    int wb = p / NPIX, n = p - (p / NPIX) * NPIX;
    int gy = wb >> 3, gx = wb & 7;
    int wy = n / WIN, wx = n - (n / WIN) * WIN;
    rmap[p] = ((gy * WIN + wy + 4) % IMG) * IMG + (gx * WIN + wx + 4) % IMG;
  }
}

// ---------------- weights -> bf16 (once) ----------------
__global__ void k_wcvt(const float* __restrict__ wqkv, const float* __restrict__ wproj,
                       ushort* __restrict__ wqb, ushort* __restrict__ wpb) {
  int i = blockIdx.x * 256 + threadIdx.x;
  const int nq = 1152 * DIM / 8;
  const int np = DIM * DIM / 8;
  if (i < nq) {
    f4 a = *(const f4*)&wqkv[i * 8];
    f4 b = *(const f4*)&wqkv[i * 8 + 4];
    us8 u; u[0]=tob(a[0]);u[1]=tob(a[1]);u[2]=tob(a[2]);u[3]=tob(a[3]);
    u[4]=tob(b[0]);u[5]=tob(b[1]);u[6]=tob(b[2]);u[7]=tob(b[3]);
    *(us8*)&wqb[i * 8] = u;
  } else if (i < nq + np) {
    int j = i - nq;
    f4 a = *(const f4*)&wproj[j * 8];
    f4 b = *(const f4*)&wproj[j * 8 + 4];
    us8 u; u[0]=tob(a[0]);u[1]=tob(a[1]);u[2]=tob(a[2]);u[3]=tob(a[3]);
    u[4]=tob(b[0]);u[5]=tob(b[1]);u[6]=tob(b[2]);u[7]=tob(b[3]);
    *(us8*)&wpb[j * 8] = u;
  }
}

// ---------------- x -> xw[b][p'][c] bf16, window-ordered, roll folded -------
__global__ __launch_bounds__(256) void k_xw(const float* __restrict__ x,
                                            const int* __restrict__ rmap,
                                            ushort* __restrict__ xw) {
  int gid = blockIdx.x * 256 + threadIdx.x;
  int b = gid / NPF, p = gid - (gid / NPF) * NPF;
  int sp = rmap[p];
  const float* xs = x + (size_t)b * DIM * NPF + sp;
  ushort* xd = xw + ((size_t)b * NPF + p) * DIM;
  for (int c0 = 0; c0 < DIM; c0 += 8) {
    us8 u;
#pragma unroll
    for (int i = 0; i < 8; ++i) u[i] = tob(xs[(size_t)(c0 + i) * NPF]);
    *(us8*)&xd[c0] = u;
  }
}

// ---------------- FUSED: qkv projection + attention per window --------------
// Block = 1 window (49 px), 256 thr = 4 waves. 3 chunks x 4 heads; wave = head.
// LDS: region0 = qt[64][136] + kt[64][136] (overlaid by pa_w[64][72] x4),
//      vs[128][72]. Q/K transposed at GEMM epilogue; V lands d-major.
__global__ __launch_bounds__(256, 2) void k_fused(const ushort* __restrict__ xw,
                                                  const ushort* __restrict__ wqb,
                                                  const float* __restrict__ bias,
                                                  ushort* __restrict__ yw) {
  __shared__ __align__(16) ushort region0[18432];   // 36864 B
  __shared__ __align__(16) ushort vs_[128 * 72];    // 18432 B
  ushort* qt = region0;                             // [64][136]
  ushort* kt = region0 + 8704;                      // [64][136]

  int t   = threadIdx.x;
  int bid = blockIdx.x;
  int wb  = (bid & 7) * 128 + (bid >> 3);           // 1024 = 8*128, bijective
  int bb  = wb >> 6;
  int w49 = (wb & 63) * NPIX;

  int lane = t & 63, wv = t >> 6;
  int l15 = lane & 15, l4 = lane >> 4;
  int wbase = wv * 96;
  ushort* pa = region0 + wv * 4608;                 // [64][72], overlays qt/kt

  // B-operand bases (xw window rows), shared by all chunks
  const ushort* bBase[4];
#pragma unroll
  for (int ni = 0; ni < 4; ++ni) {
    int px = w49 + ni * 16 + l15;
    if (px >= NPF) px = NPF - 1;
    bBase[ni] = xw + ((size_t)bb * NPF + px) * DIM + l4 * 8;
  }

  for (int c = 0; c < 3; ++c) {
    // ---- GEMM: 384 W-rows x 384 k x 64 px; wave tile 96 x 64 (global->reg->MFMA)
    const ushort* aBase[6];
    int part_[6], col_[6];
#pragma unroll
    for (int mi = 0; mi < 6; ++mi) {
      int obase = wbase + mi * 16;
      int part = obase >> 7, within = obase & 127;
      part_[mi] = part;
      col_[mi] = within + (l4 << 2);
      aBase[mi] = wqb + ((size_t)(part * DIM + c * 128 + within + l15)) * DIM + l4 * 8;
    }
    f32x4 acc[6][4] = {};
#pragma unroll
    for (int ks = 0; ks < 12; ++ks) {
      short8 af[6], bf[4];
#pragma unroll
      for (int mi = 0; mi < 6; ++mi) af[mi] = *(const short8*)(aBase[mi] + ks * 32);
#pragma unroll
      for (int ni = 0; ni < 4; ++ni) bf[ni] = *(const short8*)(bBase[ni] + ks * 32);
#pragma unroll
      for (int mi = 0; mi < 6; ++mi)
#pragma unroll
        for (int ni = 0; ni < 4; ++ni)
          acc[mi][ni] = MFMA(af[mi], bf[ni], acc[mi][ni], 0, 0, 0);
    }

    __syncthreads();   // syncA: prior chunk's pa/vs reads + Y done everywhere

    // ---- epilogue: q,k transposed to qt/kt (us4); v d-major to vs
#pragma unroll
    for (int mi = 0; mi < 6; ++mi) {
      int part = part_[mi], col = col_[mi];
#pragma unroll
      for (int ni = 0; ni < 4; ++ni) {
        int px = ni * 16 + l15;
        if (part < 2) {
          us4 u;
#pragma unroll
          for (int r = 0; r < 4; ++r) u[r] = tob(acc[mi][ni][r]);
          *(us4*)&region0[part * 8704 + px * 136 + col] = u;
        } else {
#pragma unroll
          for (int r = 0; r < 4; ++r)
            vs_[(col + r) * 72 + px] = tob(acc[mi][ni][r]);
        }
      }
    }
    __syncthreads();   // syncB: qt/kt/vs complete

    // ---- QK^T for head h = c*4 + wv
    int h = c * 4 + wv;
    short8 afq[4], bfq[4];
#pragma unroll
    for (int mi = 0; mi < 4; ++mi) afq[mi] = *(const short8*)&qt[(mi * 16 + l15) * 136 + wv * 32 + l4 * 8];
#pragma unroll
    for (int ni = 0; ni < 4; ++ni) bfq[ni] = *(const short8*)&kt[(ni * 16 + l15) * 136 + wv * 32 + l4 * 8];
    f32x4 aq[4][4] = {};
#pragma unroll
    for (int mi = 0; mi < 4; ++mi)
#pragma unroll
      for (int ni = 0; ni < 4; ++ni)
        aq[mi][ni] = MFMA(afq[mi], bfq[ni], aq[mi][ni], 0, 0, 0);

    // ---- in-register softmax (rows n = mi*16 + l4*4 + r, cols m = ni*16+l15)
    const float scale = 0.17677669529663687f;
    const float* bh = bias + h * NPIX * NPIX;
    float mx[16], sm[16];
#pragma unroll
    for (int mi = 0; mi < 4; ++mi)
#pragma unroll
      for (int r = 0; r < 4; ++r) {
        int n = mi * 16 + (l4 << 2) + r;
        float vmax = -3e38f;
#pragma unroll
        for (int ni = 0; ni < 4; ++ni) {
          int m = ni * 16 + l15;
          float s = (m < NPIX)
                      ? aq[mi][ni][r] * scale + ((n < NPIX) ? bh[n * NPIX + m] : 0.f)
                      : -3e38f;
          aq[mi][ni][r] = s;
          vmax = fmaxf(vmax, s);
        }
        mx[mi * 4 + r] = vmax;
      }
#pragma unroll
    for (int i = 1; i < 16; i <<= 1)
#pragma unroll
      for (int j = 0; j < 16; ++j) mx[j] = fmaxf(mx[j], __shfl_xor(mx[j], i));
#pragma unroll
    for (int mi = 0; mi < 4; ++mi)
#pragma unroll
      for (int r = 0; r < 4; ++r) {
        float s = 0.f;
#pragma unroll
        for (int ni = 0; ni < 4; ++ni) {
          float e = expf(aq[mi][ni][r] - mx[mi * 4 + r]);
          aq[mi][ni][r] = e;
          s += e;
        }
        sm[mi * 4 + r] = s;
      }
#pragma unroll
    for (int i = 1; i < 16; i <<= 1)
#pragma unroll
      for (int j = 0; j < 16; ++j) sm[j] += __shfl_xor(sm[j], i);

    __syncthreads();   // syncC: all waves' qt/kt frag reads done -> pa may overwrite

#pragma unroll
    for (int mi = 0; mi < 4; ++mi)
#pragma unroll
      for (int r = 0; r < 4; ++r) {
        float ri = 1.f / sm[mi * 4 + r];
        int n = mi * 16 + (l4 << 2) + r;
#pragma unroll
        for (int ni = 0; ni < 4; ++ni)
          pa[n * 72 + ni * 16 + l15] = tob(aq[mi][ni][r] * ri);
      }
    // pa is wave-private: no barrier (within-wave DS ordering)

    // ---- PV: Y[n][d32] = P . V
    f32x4 yac[4][2] = {};
#pragma unroll
    for (int ks = 0; ks < 2; ++ks) {
      short8 pf[4], vf[2];
#pragma unroll
      for (int mi = 0; mi < 4; ++mi) pf[mi] = *(const short8*)&pa[(mi * 16 + l15) * 72 + ks * 32 + l4 * 8];
#pragma unroll
      for (int nd = 0; nd < 2; ++nd) vf[nd] = *(const short8*)&vs_[(wv * 32 + nd * 16 + l15) * 72 + ks * 32 + l4 * 8];
#pragma unroll
      for (int mi = 0; mi < 4; ++mi)
#pragma unroll
        for (int nd = 0; nd < 2; ++nd)
          yac[mi][nd] = MFMA(pf[mi], vf[nd], yac[mi][nd], 0, 0, 0);
    }

    // ---- Y: transpose via pa (dead after PV), then coalesced us8 stores
#pragma unroll
    for (int mi = 0; mi < 4; ++mi)
#pragma unroll
      for (int nd = 0; nd < 2; ++nd)
#pragma unroll
        for (int r = 0; r < 4; ++r)
          pa[(mi * 16 + (l4 << 2) + r) * 72 + nd * 16 + l15] = tob(yac[mi][nd][r]);
    if (lane < NPIX) {
      size_t gb = ((size_t)bb * NPF + w49 + lane) * DIM + h * HD;
#pragma unroll
      for (int s = 0; s < 4; ++s)
        *(us8*)&yw[gb + s * 8] = *(const us8*)&pa[lane * 72 + s * 8];
    }
  }
}

// ---------------- proj: out[b][o][p] = Wp . Y  (r12 reg-staged form) --------
__global__ __launch_bounds__(256) void k_proj_pm(const ushort* __restrict__ yw,
                                                 const ushort* __restrict__ wpb,
                                                 float* __restrict__ out) {
  __shared__ __align__(16) ushort sA[2][128 * 40];
  __shared__ __align__(16) ushort sB[2][128 * 40];
  __shared__ int srm[128];
  int t   = threadIdx.x;
  int bid = blockIdx.x;
  int swz = (bid & 7) * 150 + (bid >> 3);   // 1200 = 8*150
  int o0  = (swz % 3) * 128;
  int pb  = swz / 3;
  int p0  = (pb % 25) * 128;
  int b   = pb / 25;
  if (t < 128) {
    int pg = p0 + t;
    if (pg >= NPF) pg = 0;
    int si = (pg / IMG + 53) % IMG, sj = (pg % IMG + 53) % IMG;
    srm[t] = ((si / WIN) * 8 + sj / WIN) * NPIX + (si % WIN) * WIN + (sj % WIN);
  }
  __syncthreads();

  int lane = t & 63, w = t >> 6;
  int wm = w >> 1, wn = w & 1;
  int l15 = lane & 15, l4 = lane >> 4;

  int row = t & 127, sh = (t >> 7) * 16;
  const ushort* apt = wpb + (size_t)(o0 + row) * DIM;
  const ushort* bpt = yw + ((size_t)b * NPF + srm[row]) * DIM;

  f32x4 acc[4][4] = {};

  *(us8*)&sA[0][row * 40 + sh]     = *(const us8*)&apt[sh];
  *(us8*)&sA[0][row * 40 + sh + 8] = *(const us8*)&apt[sh + 8];
  *(us8*)&sB[0][row * 40 + sh]     = *(const us8*)&bpt[sh];
  *(us8*)&sB[0][row * 40 + sh + 8] = *(const us8*)&bpt[sh + 8];

  for (int ks = 0; ks < 12; ++ks) {
    __syncthreads();
    int cur = ks & 1;
    us8 a0, a1, b0, b1;
    if (ks < 11) {
      int k0 = (ks + 1) * 32;
      a0 = *(const us8*)&apt[k0 + sh]; a1 = *(const us8*)&apt[k0 + sh + 8];
      b0 = *(const us8*)&bpt[k0 + sh]; b1 = *(const us8*)&bpt[k0 + sh + 8];
    }
    short8 af[4], bfr[4];
#pragma unroll
    for (int mi = 0; mi < 4; ++mi)
      af[mi] = *(const short8*)&sA[cur][(wm * 64 + mi * 16 + l15) * 40 + l4 * 8];
#pragma unroll
    for (int ni = 0; ni < 4; ++ni)
      bfr[ni] = *(const short8*)&sB[cur][(wn * 64 + ni * 16 + l15) * 40 + l4 * 8];
#pragma unroll
    for (int mi = 0; mi < 4; ++mi)
#pragma unroll
      for (int ni = 0; ni < 4; ++ni)
        acc[mi][ni] = MFMA(af[mi], bfr[ni], acc[mi][ni], 0, 0, 0);
    if (ks < 11) {
      int nxt = cur ^ 1;
      *(us8*)&sA[nxt][row * 40 + sh]     = a0;
      *(us8*)&sA[nxt][row * 40 + sh + 8] = a1;
      *(us8*)&sB[nxt][row * 40 + sh]     = b0;
      *(us8*)&sB[nxt][row * 40 + sh + 8] = b1;
    }
  }

  for (int mi = 0; mi < 4; ++mi)
    for (int ni = 0; ni < 4; ++ni)
      for (int r = 0; r < 4; ++r) {
        int o = o0 + wm * 64 + mi * 16 + (l4 << 2) + r;
        int p = p0 + wn * 64 + ni * 16 + l15;
        if (p < NPF)
          out[((size_t)b * DIM + o) * NPF + p] = acc[mi][ni][r];
      }
}

extern "C" void kernel_launch(void* const* d_in, const int* in_sizes, int n_in,
                              void* d_out, int out_size, void* d_ws, size_t ws_size,
                              hipStream_t stream) {
  const float* x     = (const float*)d_in[0];
  const float* wqkv  = (const float*)d_in[1];
  const float* wproj = (const float*)d_in[2];
  const float* cpb   = (const float*)d_in[3];
  float* out = (float*)d_out;

  char* ws = (char*)d_ws;
  float* bias = (float*)ws;                       // 115248 B
  int*   rmap = (int*)(ws + 115712);              // -> 131072
  ushort* wqb = (ushort*)(ws + 131072);           // 884736 B
  ushort* wpb = (ushort*)(ws + 1015808);          // 294912 B -> 1310720
  const size_t YW_B = (size_t)16 * NPF * DIM * 2; // 38.5 MB
  ushort* yw  = (ushort*)(ws + 1310720);
  ushort* xw  = (ushort*)(ws + 1310720 + YW_B);   // total ~78.4 MB (< proven 155 MB)

  hipLaunchKernelGGL(k_bias, dim3(113), dim3(256), 0, stream, cpb, bias);
  hipLaunchKernelGGL(k_rmap, dim3(13), dim3(256), 0, stream, rmap);
  hipLaunchKernelGGL(k_wcvt, dim3(288), dim3(256), 0, stream, wqkv, wproj, wqb, wpb);
  hipLaunchKernelGGL(k_xw, dim3(196), dim3(256), 0, stream, x, rmap, xw);
  hipLaunchKernelGGL(k_fused, dim3(NWIN), dim3(256), 0, stream, xw, wqb, bias, yw);
  hipLaunchKernelGGL(k_proj_pm, dim3(1200), dim3(256), 0, stream, yw, wpb, out);
}

// Round 17
// 320.786 us; speedup vs baseline: 1.3044x; 1.3044x over previous
//
#include <hip/hip_runtime.h>
#include <hip/hip_bf16.h>
#include <math.h>

#define DIM   384
#define HEADS 12
#define HD    32
#define WIN   7
#define NPIX  49
#define IMG   56
#define NPF   3136
#define NWIN  1024

typedef __attribute__((ext_vector_type(8))) short short8;
typedef __attribute__((ext_vector_type(4))) float f32x4;
typedef __attribute__((ext_vector_type(4))) float f4;
typedef __attribute__((ext_vector_type(4))) unsigned short us4;
typedef __attribute__((ext_vector_type(8))) unsigned short us8;
#define MFMA __builtin_amdgcn_mfma_f32_16x16x32_bf16

__device__ inline ushort tob(float f) {
  unsigned u; __builtin_memcpy(&u, &f, 4);
  u += 0x7fffu + ((u >> 16) & 1u);
  return (ushort)(u >> 16);
}

// ---------------- bias table ----------------
__global__ void k_bias(const float* __restrict__ cpb, float* __restrict__ bias) {
  int idx = blockIdx.x * 256 + threadIdx.x;
  if (idx >= HEADS * NPIX * NPIX) return;
  int m = idx % NPIX;
  int n = (idx / NPIX) % NPIX;
  int h = idx / (NPIX * NPIX);
  int sy = (n / WIN - m / WIN) + (WIN - 1);
  int sx = (n % WIN - m % WIN) + (WIN - 1);
  const double inv_log_beta = 1.0 / log(1.3);
  double fy = (sy == 0 ? 0.0 : log1p((double)sy) * inv_log_beta) + 6.0;
  double fx = (sx == 0 ? 0.0 : log1p((double)sx) * inv_log_beta) + 6.0;
  fy = fmin(12.0, fmax(0.0, fy));
  fx = fmin(12.0, fmax(0.0, fx));
  int ridx = (int)(fy * 13.0 + fx);
  bias[idx] = cpb[ridx * HEADS + h];
}

__global__ void k_rmap(int* __restrict__ rmap) {
  int p = blockIdx.x * 256 + threadIdx.x;
  if (p < NPF) {
    int wb = p / NPIX, n = p - (p / NPIX) * NPIX;
    int gy = wb >> 3, gx = wb & 7;
    int wy = n / WIN, wx = n - (n / WIN) * WIN;
    rmap[p] = ((gy * WIN + wy + 4) % IMG) * IMG + (gx * WIN + wx + 4) % IMG;
  }
}

// ---------------- weights -> bf16 (once) ----------------
__global__ void k_wcvt(const float* __restrict__ wqkv, const float* __restrict__ wproj,
                       ushort* __restrict__ wqb, ushort* __restrict__ wpb) {
  int i = blockIdx.x * 256 + threadIdx.x;
  const int nq = 1152 * DIM / 8;
  const int np = DIM * DIM / 8;
  if (i < nq) {
    f4 a = *(const f4*)&wqkv[i * 8];
    f4 b = *(const f4*)&wqkv[i * 8 + 4];
    us8 u; u[0]=tob(a[0]);u[1]=tob(a[1]);u[2]=tob(a[2]);u[3]=tob(a[3]);
    u[4]=tob(b[0]);u[5]=tob(b[1]);u[6]=tob(b[2]);u[7]=tob(b[3]);
    *(us8*)&wqb[i * 8] = u;
  } else if (i < nq + np) {
    int j = i - nq;
    f4 a = *(const f4*)&wproj[j * 8];
    f4 b = *(const f4*)&wproj[j * 8 + 4];
    us8 u; u[0]=tob(a[0]);u[1]=tob(a[1]);u[2]=tob(a[2]);u[3]=tob(a[3]);
    u[4]=tob(b[0]);u[5]=tob(b[1]);u[6]=tob(b[2]);u[7]=tob(b[3]);
    *(us8*)&wpb[j * 8] = u;
  }
}

// ---------------- x -> xw[b][p'][c] bf16, window-ordered, roll folded -------
__global__ __launch_bounds__(256) void k_xw(const float* __restrict__ x,
                                            const int* __restrict__ rmap,
                                            ushort* __restrict__ xw) {
  int gid = blockIdx.x * 256 + threadIdx.x;
  int b = gid / NPF, p = gid - (gid / NPF) * NPF;
  int sp = rmap[p];
  const float* xs = x + (size_t)b * DIM * NPF + sp;
  ushort* xd = xw + ((size_t)b * NPF + p) * DIM;
  for (int c0 = 0; c0 < DIM; c0 += 8) {
    us8 u;
#pragma unroll
    for (int i = 0; i < 8; ++i) u[i] = tob(xs[(size_t)(c0 + i) * NPF]);
    *(us8*)&xd[c0] = u;
  }
}

// ---------------- QKV GEMM (r12 verbatim): block 128(o) x 256(p) ------------
__global__ __launch_bounds__(256) void k_qkv_pm(const ushort* __restrict__ xw,
                                                const ushort* __restrict__ wqb,
                                                ushort* __restrict__ qkv) {
  __shared__ __align__(16) ushort sA[2][128 * 40];
  __shared__ __align__(16) ushort sB[2][256 * 40];
  int t   = threadIdx.x;
  int bid = blockIdx.x;
  int swz = (bid & 7) * 234 + (bid >> 3);   // 1872 = 8*234, bijective
  int o0  = (swz % 9) * 128;
  int pbt = swz / 9;
  int p0  = (pbt % 13) * 256;
  int b   = pbt / 13;

  int lane = t & 63, w = t >> 6;
  int wm = w >> 1, wn = w & 1;
  int l15 = lane & 15, l4 = lane >> 4;

  int arow = t & 127, ash = (t >> 7) * 16;
  const ushort* apt = wqb + (size_t)(o0 + arow) * DIM + ash;
  int brow = t;
  int prow = p0 + brow; if (prow >= NPF) prow = NPF - 1;
  const ushort* bpt = xw + ((size_t)b * NPF + prow) * DIM;

  f32x4 acc[4][8] = {};

  *(us8*)&sA[0][arow * 40 + ash]     = *(const us8*)&apt[0];
  *(us8*)&sA[0][arow * 40 + ash + 8] = *(const us8*)&apt[8];
#pragma unroll
  for (int j = 0; j < 4; ++j)
    *(us8*)&sB[0][brow * 40 + j * 8] = *(const us8*)&bpt[j * 8];

  for (int ks = 0; ks < 12; ++ks) {
    __syncthreads();
    int cur = ks & 1;
    us8 a0, a1, b0, b1, b2, b3;
    if (ks < 11) {
      int k0 = (ks + 1) * 32;
      a0 = *(const us8*)&apt[k0];
      a1 = *(const us8*)&apt[k0 + 8];
      b0 = *(const us8*)&bpt[k0];
      b1 = *(const us8*)&bpt[k0 + 8];
      b2 = *(const us8*)&bpt[k0 + 16];
      b3 = *(const us8*)&bpt[k0 + 24];
    }
    short8 af[4], bfr[8];
#pragma unroll
    for (int mi = 0; mi < 4; ++mi)
      af[mi] = *(const short8*)&sA[cur][(wm * 64 + mi * 16 + l15) * 40 + l4 * 8];
#pragma unroll
    for (int ni = 0; ni < 8; ++ni)
      bfr[ni] = *(const short8*)&sB[cur][(wn * 128 + ni * 16 + l15) * 40 + l4 * 8];
#pragma unroll
    for (int mi = 0; mi < 4; ++mi)
#pragma unroll
      for (int ni = 0; ni < 8; ++ni)
        acc[mi][ni] = MFMA(af[mi], bfr[ni], acc[mi][ni], 0, 0, 0);
    if (ks < 11) {
      int nxt = cur ^ 1;
      *(us8*)&sA[nxt][arow * 40 + ash]     = a0;
      *(us8*)&sA[nxt][arow * 40 + ash + 8] = a1;
      *(us8*)&sB[nxt][brow * 40]      = b0;
      *(us8*)&sB[nxt][brow * 40 + 8]  = b1;
      *(us8*)&sB[nxt][brow * 40 + 16] = b2;
      *(us8*)&sB[nxt][brow * 40 + 24] = b3;
    }
  }

#pragma unroll
  for (int mi = 0; mi < 4; ++mi)
#pragma unroll
    for (int ni = 0; ni < 8; ++ni) {
      int p = p0 + wn * 128 + ni * 16 + l15;
      if (p < NPF) {
        us4 u;
#pragma unroll
        for (int r = 0; r < 4; ++r) u[r] = tob(acc[mi][ni][r]);
        *(us4*)&qkv[((size_t)b * NPF + p) * 1152 + o0 + wm * 64 + mi * 16 + (l4 << 2)] = u;
      }
    }
}

// ---------------- attention (r12 verbatim) ----------------
__global__ __launch_bounds__(64) void k_attn_pm(ushort* __restrict__ qkv,
                                                const float* __restrict__ bias) {
  __shared__ __align__(16) ushort smem[8992];
  ushort* sq  = smem;          // [64][40]
  ushort* skt = smem + 2560;   // [64][40]
  ushort* svt = smem + 5120;   // [32][72]
  ushort* stg = smem + 7424;   // [49][32]
  ushort* pa  = smem;          // [64][72] overlays sq/skt

  int t = threadIdx.x;
  int bid = blockIdx.x;
  int swz = (bid & 7) * 1536 + (bid >> 3);   // 12288 = 8*1536
  int h = swz % HEADS, wb = swz / HEADS;
  int b = wb >> 6;
  int w49 = (wb & 63) * NPIX;
  ushort* qrow = qkv + ((size_t)b * NPF + w49) * 1152 + h * HD;

  for (int idx = t; idx < 32 * 23; idx += 64) {
    int d = idx / 23, mm = 49 + (idx - (idx / 23) * 23);
    svt[d * 72 + mm] = 0;
  }
  for (int idx = t; idx < NPIX * 4; idx += 64) {
    int n = idx >> 2, s = (idx & 3) * 8;
    *(us8*)&sq [n * 40 + s] = *(const us8*)&qrow[(size_t)n * 1152 + s];
    *(us8*)&skt[n * 40 + s] = *(const us8*)&qrow[(size_t)n * 1152 + DIM + s];
    *(us8*)&stg[n * 32 + s] = *(const us8*)&qrow[(size_t)n * 1152 + 2 * DIM + s];
  }
  __syncthreads();
  for (int idx = t; idx < HD * NPIX; idx += 64) {
    int d = idx / NPIX, m = idx - d * NPIX;
    svt[d * 72 + m] = stg[m * 32 + d];
  }
  __syncthreads();

  int l15 = t & 15, l4 = t >> 4;
  f32x4 acc[4][4] = {};
  {
    short8 af[4], bfr[4];
#pragma unroll
    for (int mi = 0; mi < 4; ++mi) af[mi]  = *(const short8*)&sq [(mi * 16 + l15) * 40 + l4 * 8];
#pragma unroll
    for (int ni = 0; ni < 4; ++ni) bfr[ni] = *(const short8*)&skt[(ni * 16 + l15) * 40 + l4 * 8];
#pragma unroll
    for (int mi = 0; mi < 4; ++mi)
#pragma unroll
      for (int ni = 0; ni < 4; ++ni)
        acc[mi][ni] = MFMA(af[mi], bfr[ni], acc[mi][ni], 0, 0, 0);
  }

  const float scale = 0.17677669529663687f;
  const float* bh = bias + h * NPIX * NPIX;
  float mx[16], sm[16];
#pragma unroll
  for (int mi = 0; mi < 4; ++mi)
#pragma unroll
    for (int r = 0; r < 4; ++r) {
      int n = mi * 16 + (l4 << 2) + r;
      float vmax = -3e38f;
#pragma unroll
      for (int ni = 0; ni < 4; ++ni) {
        int m = ni * 16 + l15;
        float s = (m < NPIX)
                    ? acc[mi][ni][r] * scale + ((n < NPIX) ? bh[n * NPIX + m] : 0.f)
                    : -3e38f;
        acc[mi][ni][r] = s;
        vmax = fmaxf(vmax, s);
      }
      mx[mi * 4 + r] = vmax;
    }
#pragma unroll
  for (int i = 1; i < 16; i <<= 1)
#pragma unroll
    for (int j = 0; j < 16; ++j) mx[j] = fmaxf(mx[j], __shfl_xor(mx[j], i));
#pragma unroll
  for (int mi = 0; mi < 4; ++mi)
#pragma unroll
    for (int r = 0; r < 4; ++r) {
      float s = 0.f;
#pragma unroll
      for (int ni = 0; ni < 4; ++ni) {
        float e = expf(acc[mi][ni][r] - mx[mi * 4 + r]);
        acc[mi][ni][r] = e;
        s += e;
      }
      sm[mi * 4 + r] = s;
    }
#pragma unroll
  for (int i = 1; i < 16; i <<= 1)
#pragma unroll
    for (int j = 0; j < 16; ++j) sm[j] += __shfl_xor(sm[j], i);

  __syncthreads();
#pragma unroll
  for (int mi = 0; mi < 4; ++mi)
#pragma unroll
    for (int r = 0; r < 4; ++r) {
      float ri = 1.f / sm[mi * 4 + r];
      int n = mi * 16 + (l4 << 2) + r;
#pragma unroll
      for (int ni = 0; ni < 4; ++ni)
        pa[n * 72 + ni * 16 + l15] = tob(acc[mi][ni][r] * ri);
    }
  __syncthreads();

  f32x4 yac[4][2] = {};
#pragma unroll
  for (int ks = 0; ks < 2; ++ks) {
    short8 pf[4], vf[2];
#pragma unroll
    for (int mi = 0; mi < 4; ++mi) pf[mi] = *(const short8*)&pa [(mi * 16 + l15) * 72 + ks * 32 + l4 * 8];
#pragma unroll
    for (int nd = 0; nd < 2; ++nd) vf[nd] = *(const short8*)&svt[(nd * 16 + l15) * 72 + ks * 32 + l4 * 8];
#pragma unroll
    for (int mi = 0; mi < 4; ++mi)
#pragma unroll
      for (int nd = 0; nd < 2; ++nd)
        yac[mi][nd] = MFMA(pf[mi], vf[nd], yac[mi][nd], 0, 0, 0);
  }
#pragma unroll
  for (int mi = 0; mi < 4; ++mi)
#pragma unroll
    for (int nd = 0; nd < 2; ++nd) {
      int nb = mi * 16 + (l4 << 2);
      int d = nd * 16 + l15;
#pragma unroll
      for (int r = 0; r < 4; ++r)
        if (nb + r < NPIX) qrow[(size_t)(nb + r) * 1152 + d] = tob(yac[mi][nd][r]);
    }
}

// ---------------- proj GEMM: r12-qkv structure, 128(o) x 256(p) -------------
// grid 624 = 3 x 13 x 16, XCD-swizzled, o fastest. B rows gathered via srm.
__global__ __launch_bounds__(256) void k_proj_pm(const ushort* __restrict__ qkv,
                                                 const ushort* __restrict__ wpb,
                                                 float* __restrict__ out) {
  __shared__ __align__(16) ushort sA[2][128 * 40];
  __shared__ __align__(16) ushort sB[2][256 * 40];
  __shared__ int srm[256];
  int t   = threadIdx.x;
  int bid = blockIdx.x;
  int swz = (bid & 7) * 78 + (bid >> 3);    // 624 = 8*78, bijective
  int o0  = (swz % 3) * 128;
  int pbt = swz / 3;
  int p0  = (pbt % 13) * 256;
  int b   = pbt / 13;
  {
    int pg = p0 + t;
    if (pg >= NPF) pg = 0;
    int si = (pg / IMG + 53) % IMG, sj = (pg % IMG + 53) % IMG;  // inverse roll +3
    srm[t] = ((si / WIN) * 8 + sj / WIN) * NPIX + (si % WIN) * WIN + (sj % WIN);
  }
  __syncthreads();

  int lane = t & 63, w = t >> 6;
  int wm = w >> 1, wn = w & 1;
  int l15 = lane & 15, l4 = lane >> 4;

  int arow = t & 127, ash = (t >> 7) * 16;
  const ushort* apt = wpb + (size_t)(o0 + arow) * DIM + ash;
  int brow = t;
  const ushort* bpt = qkv + ((size_t)b * NPF + srm[brow]) * 1152;

  f32x4 acc[4][8] = {};

  *(us8*)&sA[0][arow * 40 + ash]     = *(const us8*)&apt[0];
  *(us8*)&sA[0][arow * 40 + ash + 8] = *(const us8*)&apt[8];
#pragma unroll
  for (int j = 0; j < 4; ++j)
    *(us8*)&sB[0][brow * 40 + j * 8] = *(const us8*)&bpt[j * 8];

  for (int ks = 0; ks < 12; ++ks) {
    __syncthreads();
    int cur = ks & 1;
    us8 a0, a1, b0, b1, b2, b3;
    if (ks < 11) {
      int k0 = (ks + 1) * 32;
      a0 = *(const us8*)&apt[k0];
      a1 = *(const us8*)&apt[k0 + 8];
      b0 = *(const us8*)&bpt[k0];
      b1 = *(const us8*)&bpt[k0 + 8];
      b2 = *(const us8*)&bpt[k0 + 16];
      b3 = *(const us8*)&bpt[k0 + 24];
    }
    short8 af[4], bfr[8];
#pragma unroll
    for (int mi = 0; mi < 4; ++mi)
      af[mi] = *(const short8*)&sA[cur][(wm * 64 + mi * 16 + l15) * 40 + l4 * 8];
#pragma unroll
    for (int ni = 0; ni < 8; ++ni)
      bfr[ni] = *(const short8*)&sB[cur][(wn * 128 + ni * 16 + l15) * 40 + l4 * 8];
#pragma unroll
    for (int mi = 0; mi < 4; ++mi)
#pragma unroll
      for (int ni = 0; ni < 8; ++ni)
        acc[mi][ni] = MFMA(af[mi], bfr[ni], acc[mi][ni], 0, 0, 0);
    if (ks < 11) {
      int nxt = cur ^ 1;
      *(us8*)&sA[nxt][arow * 40 + ash]     = a0;
      *(us8*)&sA[nxt][arow * 40 + ash + 8] = a1;
      *(us8*)&sB[nxt][brow * 40]      = b0;
      *(us8*)&sB[nxt][brow * 40 + 8]  = b1;
      *(us8*)&sB[nxt][brow * 40 + 16] = b2;
      *(us8*)&sB[nxt][brow * 40 + 24] = b3;
    }
  }

#pragma unroll
  for (int mi = 0; mi < 4; ++mi)
#pragma unroll
    for (int ni = 0; ni < 8; ++ni) {
      int p = p0 + wn * 128 + ni * 16 + l15;
      if (p < NPF) {
#pragma unroll
        for (int r = 0; r < 4; ++r) {
          int o = o0 + wm * 64 + mi * 16 + (l4 << 2) + r;
          out[((size_t)b * DIM + o) * NPF + p] = acc[mi][ni][r];
        }
      }
    }
}

extern "C" void kernel_launch(void* const* d_in, const int* in_sizes, int n_in,
                              void* d_out, int out_size, void* d_ws, size_t ws_size,
                              hipStream_t stream) {
  const float* x     = (const float*)d_in[0];
  const float* wqkv  = (const float*)d_in[1];
  const float* wproj = (const float*)d_in[2];
  const float* cpb   = (const float*)d_in[3];
  float* out = (float*)d_out;

  char* ws = (char*)d_ws;
  float* bias = (float*)ws;                       // 115248 B
  int*   rmap = (int*)(ws + 115712);              // -> 131072
  ushort* wqb = (ushort*)(ws + 131072);           // 884736 B
  ushort* wpb = (ushort*)(ws + 1015808);          // 294912 B -> 1310720
  const size_t QKV_B = (size_t)16 * 1152 * NPF * 2;   // 115.6 MB
  ushort* qkv = (ushort*)(ws + 1310720);
  ushort* xw  = (ushort*)(ws + 1310720 + QKV_B);      // 38.5 MB (ws >= 155.5 MB proven)

  hipLaunchKernelGGL(k_bias, dim3(113), dim3(256), 0, stream, cpb, bias);
  hipLaunchKernelGGL(k_rmap, dim3(13), dim3(256), 0, stream, rmap);
  hipLaunchKernelGGL(k_wcvt, dim3(288), dim3(256), 0, stream, wqkv, wproj, wqb, wpb);
  hipLaunchKernelGGL(k_xw, dim3(196), dim3(256), 0, stream, x, rmap, xw);
  hipLaunchKernelGGL(k_qkv_pm, dim3(1872), dim3(256), 0, stream, xw, wqb, qkv);
  hipLaunchKernelGGL(k_attn_pm, dim3(NWIN * HEADS), dim3(64), 0, stream, qkv, bias);
  hipLaunchKernelGGL(k_proj_pm, dim3(624), dim3(256), 0, stream, qkv, wpb, out);
}

// Round 19
// 312.240 us; speedup vs baseline: 1.3401x; 1.0274x over previous
//
#include <hip/hip_runtime.h>
#include <hip/hip_bf16.h>
#include <math.h>

#define DIM   384
#define HEADS 12
#define HD    32
#define WIN   7
#define NPIX  49
#define IMG   56
#define NPF   3136
#define NWIN  1024

typedef __attribute__((ext_vector_type(8))) short short8;
typedef __attribute__((ext_vector_type(4))) float f32x4;
typedef __attribute__((ext_vector_type(4))) float f4;
typedef __attribute__((ext_vector_type(4))) unsigned short us4;
typedef __attribute__((ext_vector_type(8))) unsigned short us8;
#define MFMA __builtin_amdgcn_mfma_f32_16x16x32_bf16

__device__ inline ushort tob(float f) {
  unsigned u; __builtin_memcpy(&u, &f, 4);
  u += 0x7fffu + ((u >> 16) & 1u);
  return (ushort)(u >> 16);
}

// ---------------- bias table ----------------
__global__ void k_bias(const float* __restrict__ cpb, float* __restrict__ bias) {
  int idx = blockIdx.x * 256 + threadIdx.x;
  if (idx >= HEADS * NPIX * NPIX) return;
  int m = idx % NPIX;
  int n = (idx / NPIX) % NPIX;
  int h = idx / (NPIX * NPIX);
  int sy = (n / WIN - m / WIN) + (WIN - 1);
  int sx = (n % WIN - m % WIN) + (WIN - 1);
  const double inv_log_beta = 1.0 / log(1.3);
  double fy = (sy == 0 ? 0.0 : log1p((double)sy) * inv_log_beta) + 6.0;
  double fx = (sx == 0 ? 0.0 : log1p((double)sx) * inv_log_beta) + 6.0;
  fy = fmin(12.0, fmax(0.0, fy));
  fx = fmin(12.0, fmax(0.0, fx));
  int ridx = (int)(fy * 13.0 + fx);
  bias[idx] = cpb[ridx * HEADS + h];
}

__global__ void k_rmap(int* __restrict__ rmap) {
  int p = blockIdx.x * 256 + threadIdx.x;
  if (p < NPF) {
    int wb = p / NPIX, n = p - (p / NPIX) * NPIX;
    int gy = wb >> 3, gx = wb & 7;
    int wy = n / WIN, wx = n - (n / WIN) * WIN;
    rmap[p] = ((gy * WIN + wy + 4) % IMG) * IMG + (gx * WIN + wx + 4) % IMG;
  }
}

// ---------------- weights -> bf16 (once) ----------------
__global__ void k_wcvt(const float* __restrict__ wqkv, const float* __restrict__ wproj,
                       ushort* __restrict__ wqb, ushort* __restrict__ wpb) {
  int i = blockIdx.x * 256 + threadIdx.x;
  const int nq = 1152 * DIM / 8;
  const int np = DIM * DIM / 8;
  if (i < nq) {
    f4 a = *(const f4*)&wqkv[i * 8];
    f4 b = *(const f4*)&wqkv[i * 8 + 4];
    us8 u; u[0]=tob(a[0]);u[1]=tob(a[1]);u[2]=tob(a[2]);u[3]=tob(a[3]);
    u[4]=tob(b[0]);u[5]=tob(b[1]);u[6]=tob(b[2]);u[7]=tob(b[3]);
    *(us8*)&wqb[i * 8] = u;
  } else if (i < nq + np) {
    int j = i - nq;
    f4 a = *(const f4*)&wproj[j * 8];
    f4 b = *(const f4*)&wproj[j * 8 + 4];
    us8 u; u[0]=tob(a[0]);u[1]=tob(a[1]);u[2]=tob(a[2]);u[3]=tob(a[3]);
    u[4]=tob(b[0]);u[5]=tob(b[1]);u[6]=tob(b[2]);u[7]=tob(b[3]);
    *(us8*)&wpb[j * 8] = u;
  }
}

// ---------------- x -> xw[b][p'][c] bf16, window-ordered, roll folded -------
__global__ __launch_bounds__(256) void k_xw(const float* __restrict__ x,
                                            const int* __restrict__ rmap,
                                            ushort* __restrict__ xw) {
  int gid = blockIdx.x * 256 + threadIdx.x;
  int b = gid / NPF, p = gid - (gid / NPF) * NPF;
  int sp = rmap[p];
  const float* xs = x + (size_t)b * DIM * NPF + sp;
  ushort* xd = xw + ((size_t)b * NPF + p) * DIM;
  for (int c0 = 0; c0 < DIM; c0 += 8) {
    us8 u;
#pragma unroll
    for (int i = 0; i < 8; ++i) u[i] = tob(xs[(size_t)(c0 + i) * NPF]);
    *(us8*)&xd[c0] = u;
  }
}

// ---------------- QKV GEMM: r12 structure + 2-ahead register staging --------
__global__ __launch_bounds__(256) void k_qkv_pm(const ushort* __restrict__ xw,
                                                const ushort* __restrict__ wqb,
                                                ushort* __restrict__ qkv) {
  __shared__ __align__(16) ushort sA[2][128 * 40];
  __shared__ __align__(16) ushort sB[2][256 * 40];
  int t   = threadIdx.x;
  int bid = blockIdx.x;
  int swz = (bid & 7) * 234 + (bid >> 3);   // 1872 = 8*234, bijective
  int o0  = (swz % 9) * 128;
  int pbt = swz / 9;
  int p0  = (pbt % 13) * 256;
  int b   = pbt / 13;

  int lane = t & 63, w = t >> 6;
  int wm = w >> 1, wn = w & 1;
  int l15 = lane & 15, l4 = lane >> 4;

  int arow = t & 127, ash = (t >> 7) * 16;
  const ushort* apt = wqb + (size_t)(o0 + arow) * DIM + ash;
  int brow = t;
  int prow = p0 + brow; if (prow >= NPF) prow = NPF - 1;
  const ushort* bpt = xw + ((size_t)b * NPF + prow) * DIM;

  struct Stage { us8 a0, a1, b0, b1, b2, b3; };
  Stage st0, st1;

#define QLOAD(S, K0)                                    \
  do {                                                  \
    (S).a0 = *(const us8*)&apt[(K0)];                   \
    (S).a1 = *(const us8*)&apt[(K0) + 8];               \
    (S).b0 = *(const us8*)&bpt[(K0)];                   \
    (S).b1 = *(const us8*)&bpt[(K0) + 8];               \
    (S).b2 = *(const us8*)&bpt[(K0) + 16];              \
    (S).b3 = *(const us8*)&bpt[(K0) + 24];              \
  } while (0)
#define QWRITE(S, BUF)                                  \
  do {                                                  \
    *(us8*)&sA[(BUF)][arow * 40 + ash]     = (S).a0;    \
    *(us8*)&sA[(BUF)][arow * 40 + ash + 8] = (S).a1;    \
    *(us8*)&sB[(BUF)][brow * 40]      = (S).b0;         \
    *(us8*)&sB[(BUF)][brow * 40 + 8]  = (S).b1;         \
    *(us8*)&sB[(BUF)][brow * 40 + 16] = (S).b2;         \
    *(us8*)&sB[(BUF)][brow * 40 + 24] = (S).b3;         \
  } while (0)

  f32x4 acc[4][8] = {};

  QLOAD(st0, 0);        // G0
  QWRITE(st0, 0);
  QLOAD(st1, 32);       // G1

#pragma unroll
  for (int ks = 0; ks < 12; ++ks) {
    __syncthreads();
    // issue G(ks+2) into the freed set (whose content is already in LDS)
    if (ks < 10) {
      if ((ks & 1) == 0) QLOAD(st0, (ks + 2) * 32);
      else               QLOAD(st1, (ks + 2) * 32);
    }
    int cur = ks & 1;
    short8 af[4], bfr[8];
#pragma unroll
    for (int mi = 0; mi < 4; ++mi)
      af[mi] = *(const short8*)&sA[cur][(wm * 64 + mi * 16 + l15) * 40 + l4 * 8];
#pragma unroll
    for (int ni = 0; ni < 8; ++ni)
      bfr[ni] = *(const short8*)&sB[cur][(wn * 128 + ni * 16 + l15) * 40 + l4 * 8];
#pragma unroll
    for (int mi = 0; mi < 4; ++mi)
#pragma unroll
      for (int ni = 0; ni < 8; ++ni)
        acc[mi][ni] = MFMA(af[mi], bfr[ni], acc[mi][ni], 0, 0, 0);
    // write G(ks+1) (loaded a full iteration ago) into the next buffer
    if (ks < 11) {
      if ((ks & 1) == 0) QWRITE(st1, 1);
      else               QWRITE(st0, 0);
    }
  }
#undef QLOAD
#undef QWRITE

#pragma unroll
  for (int mi = 0; mi < 4; ++mi)
#pragma unroll
    for (int ni = 0; ni < 8; ++ni) {
      int p = p0 + wn * 128 + ni * 16 + l15;
      if (p < NPF) {
        us4 u;
#pragma unroll
        for (int r = 0; r < 4; ++r) u[r] = tob(acc[mi][ni][r]);
        *(us4*)&qkv[((size_t)b * NPF + p) * 1152 + o0 + wm * 64 + mi * 16 + (l4 << 2)] = u;
      }
    }
}

// ---------------- attention (r12 verbatim) ----------------
__global__ __launch_bounds__(64) void k_attn_pm(ushort* __restrict__ qkv,
                                                const float* __restrict__ bias) {
  __shared__ __align__(16) ushort smem[8992];
  ushort* sq  = smem;          // [64][40]
  ushort* skt = smem + 2560;   // [64][40]
  ushort* svt = smem + 5120;   // [32][72]
  ushort* stg = smem + 7424;   // [49][32]
  ushort* pa  = smem;          // [64][72] overlays sq/skt

  int t = threadIdx.x;
  int bid = blockIdx.x;
  int swz = (bid & 7) * 1536 + (bid >> 3);   // 12288 = 8*1536
  int h = swz % HEADS, wb = swz / HEADS;
  int b = wb >> 6;
  int w49 = (wb & 63) * NPIX;
  ushort* qrow = qkv + ((size_t)b * NPF + w49) * 1152 + h * HD;

  for (int idx = t; idx < 32 * 23; idx += 64) {
    int d = idx / 23, mm = 49 + (idx - (idx / 23) * 23);
    svt[d * 72 + mm] = 0;
  }
  for (int idx = t; idx < NPIX * 4; idx += 64) {
    int n = idx >> 2, s = (idx & 3) * 8;
    *(us8*)&sq [n * 40 + s] = *(const us8*)&qrow[(size_t)n * 1152 + s];
    *(us8*)&skt[n * 40 + s] = *(const us8*)&qrow[(size_t)n * 1152 + DIM + s];
    *(us8*)&stg[n * 32 + s] = *(const us8*)&qrow[(size_t)n * 1152 + 2 * DIM + s];
  }
  __syncthreads();
  for (int idx = t; idx < HD * NPIX; idx += 64) {
    int d = idx / NPIX, m = idx - d * NPIX;
    svt[d * 72 + m] = stg[m * 32 + d];
  }
  __syncthreads();

  int l15 = t & 15, l4 = t >> 4;
  f32x4 acc[4][4] = {};
  {
    short8 af[4], bfr[4];
#pragma unroll
    for (int mi = 0; mi < 4; ++mi) af[mi]  = *(const short8*)&sq [(mi * 16 + l15) * 40 + l4 * 8];
#pragma unroll
    for (int ni = 0; ni < 4; ++ni) bfr[ni] = *(const short8*)&skt[(ni * 16 + l15) * 40 + l4 * 8];
#pragma unroll
    for (int mi = 0; mi < 4; ++mi)
#pragma unroll
      for (int ni = 0; ni < 4; ++ni)
        acc[mi][ni] = MFMA(af[mi], bfr[ni], acc[mi][ni], 0, 0, 0);
  }

  const float scale = 0.17677669529663687f;
  const float* bh = bias + h * NPIX * NPIX;
  float mx[16], sm[16];
#pragma unroll
  for (int mi = 0; mi < 4; ++mi)
#pragma unroll
    for (int r = 0; r < 4; ++r) {
      int n = mi * 16 + (l4 << 2) + r;
      float vmax = -3e38f;
#pragma unroll
      for (int ni = 0; ni < 4; ++ni) {
        int m = ni * 16 + l15;
        float s = (m < NPIX)
                    ? acc[mi][ni][r] * scale + ((n < NPIX) ? bh[n * NPIX + m] : 0.f)
                    : -3e38f;
        acc[mi][ni][r] = s;
        vmax = fmaxf(vmax, s);
      }
      mx[mi * 4 + r] = vmax;
    }
#pragma unroll
  for (int i = 1; i < 16; i <<= 1)
#pragma unroll
    for (int j = 0; j < 16; ++j) mx[j] = fmaxf(mx[j], __shfl_xor(mx[j], i));
#pragma unroll
  for (int mi = 0; mi < 4; ++mi)
#pragma unroll
    for (int r = 0; r < 4; ++r) {
      float s = 0.f;
#pragma unroll
      for (int ni = 0; ni < 4; ++ni) {
        float e = expf(acc[mi][ni][r] - mx[mi * 4 + r]);
        acc[mi][ni][r] = e;
        s += e;
      }
      sm[mi * 4 + r] = s;
    }
#pragma unroll
  for (int i = 1; i < 16; i <<= 1)
#pragma unroll
    for (int j = 0; j < 16; ++j) sm[j] += __shfl_xor(sm[j], i);

  __syncthreads();
#pragma unroll
  for (int mi = 0; mi < 4; ++mi)
#pragma unroll
    for (int r = 0; r < 4; ++r) {
      float ri = 1.f / sm[mi * 4 + r];
      int n = mi * 16 + (l4 << 2) + r;
#pragma unroll
      for (int ni = 0; ni < 4; ++ni)
        pa[n * 72 + ni * 16 + l15] = tob(acc[mi][ni][r] * ri);
    }
  __syncthreads();

  f32x4 yac[4][2] = {};
#pragma unroll
  for (int ks = 0; ks < 2; ++ks) {
    short8 pf[4], vf[2];
#pragma unroll
    for (int mi = 0; mi < 4; ++mi) pf[mi] = *(const short8*)&pa [(mi * 16 + l15) * 72 + ks * 32 + l4 * 8];
#pragma unroll
    for (int nd = 0; nd < 2; ++nd) vf[nd] = *(const short8*)&svt[(nd * 16 + l15) * 72 + ks * 32 + l4 * 8];
#pragma unroll
    for (int mi = 0; mi < 4; ++mi)
#pragma unroll
      for (int nd = 0; nd < 2; ++nd)
        yac[mi][nd] = MFMA(pf[mi], vf[nd], yac[mi][nd], 0, 0, 0);
  }
#pragma unroll
  for (int mi = 0; mi < 4; ++mi)
#pragma unroll
    for (int nd = 0; nd < 2; ++nd) {
      int nb = mi * 16 + (l4 << 2);
      int d = nd * 16 + l15;
#pragma unroll
      for (int r = 0; r < 4; ++r)
        if (nb + r < NPIX) qrow[(size_t)(nb + r) * 1152 + d] = tob(yac[mi][nd][r]);
    }
}

// ---------------- proj GEMM: r12 128x128 form + 2-ahead staging -------------
__global__ __launch_bounds__(256) void k_proj_pm(const ushort* __restrict__ qkv,
                                                 const ushort* __restrict__ wpb,
                                                 float* __restrict__ out) {
  __shared__ __align__(16) ushort sA[2][128 * 40];
  __shared__ __align__(16) ushort sB[2][128 * 40];
  __shared__ int srm[128];
  int t   = threadIdx.x;
  int bid = blockIdx.x;
  int swz = (bid & 7) * 150 + (bid >> 3);   // 1200 = 8*150
  int o0  = (swz % 3) * 128;
  int pb  = swz / 3;
  int p0  = (pb % 25) * 128;
  int b   = pb / 25;
  if (t < 128) {
    int pg = p0 + t;
    if (pg >= NPF) pg = 0;
    int si = (pg / IMG + 53) % IMG, sj = (pg % IMG + 53) % IMG;
    srm[t] = ((si / WIN) * 8 + sj / WIN) * NPIX + (si % WIN) * WIN + (sj % WIN);
  }
  __syncthreads();

  int lane = t & 63, w = t >> 6;
  int wm = w >> 1, wn = w & 1;
  int l15 = lane & 15, l4 = lane >> 4;

  int row = t & 127, sh = (t >> 7) * 16;
  const ushort* apt = wpb + (size_t)(o0 + row) * DIM;
  const ushort* bpt = qkv + ((size_t)b * NPF + srm[row]) * 1152;

  struct Stage { us8 a0, a1, b0, b1; };
  Stage st0, st1;

#define PLOAD(S, K0)                                    \
  do {                                                  \
    (S).a0 = *(const us8*)&apt[(K0) + sh];              \
    (S).a1 = *(const us8*)&apt[(K0) + sh + 8];          \
    (S).b0 = *(const us8*)&bpt[(K0) + sh];              \
    (S).b1 = *(const us8*)&bpt[(K0) + sh + 8];          \
  } while (0)
#define PWRITE(S, BUF)                                  \
  do {                                                  \
    *(us8*)&sA[(BUF)][row * 40 + sh]     = (S).a0;      \
    *(us8*)&sA[(BUF)][row * 40 + sh + 8] = (S).a1;      \
    *(us8*)&sB[(BUF)][row * 40 + sh]     = (S).b0;      \
    *(us8*)&sB[(BUF)][row * 40 + sh + 8] = (S).b1;      \
  } while (0)

  f32x4 acc[4][4] = {};

  PLOAD(st0, 0);
  PWRITE(st0, 0);
  PLOAD(st1, 32);

#pragma unroll
  for (int ks = 0; ks < 12; ++ks) {
    __syncthreads();
    if (ks < 10) {
      if ((ks & 1) == 0) PLOAD(st0, (ks + 2) * 32);
      else               PLOAD(st1, (ks + 2) * 32);
    }
    int cur = ks & 1;
    short8 af[4], bfr[4];
#pragma unroll
    for (int mi = 0; mi < 4; ++mi)
      af[mi] = *(const short8*)&sA[cur][(wm * 64 + mi * 16 + l15) * 40 + l4 * 8];
#pragma unroll
    for (int ni = 0; ni < 4; ++ni)
      bfr[ni] = *(const short8*)&sB[cur][(wn * 64 + ni * 16 + l15) * 40 + l4 * 8];
#pragma unroll
    for (int mi = 0; mi < 4; ++mi)
#pragma unroll
      for (int ni = 0; ni < 4; ++ni)
        acc[mi][ni] = MFMA(af[mi], bfr[ni], acc[mi][ni], 0, 0, 0);
    if (ks < 11) {
      if ((ks & 1) == 0) PWRITE(st1, 1);
      else               PWRITE(st0, 0);
    }
  }
#undef PLOAD
#undef PWRITE

  for (int mi = 0; mi < 4; ++mi)
    for (int ni = 0; ni < 4; ++ni)
      for (int r = 0; r < 4; ++r) {
        int o = o0 + wm * 64 + mi * 16 + (l4 << 2) + r;
        int p = p0 + wn * 64 + ni * 16 + l15;
        if (p < NPF)
          out[((size_t)b * DIM + o) * NPF + p] = acc[mi][ni][r];
      }
}

extern "C" void kernel_launch(void* const* d_in, const int* in_sizes, int n_in,
                              void* d_out, int out_size, void* d_ws, size_t ws_size,
                              hipStream_t stream) {
  const float* x     = (const float*)d_in[0];
  const float* wqkv  = (const float*)d_in[1];
  const float* wproj = (const float*)d_in[2];
  const float* cpb   = (const float*)d_in[3];
  float* out = (float*)d_out;

  char* ws = (char*)d_ws;
  float* bias = (float*)ws;                       // 115248 B
  int*   rmap = (int*)(ws + 115712);              // -> 131072
  ushort* wqb = (ushort*)(ws + 131072);           // 884736 B
  ushort* wpb = (ushort*)(ws + 1015808);          // 294912 B -> 1310720
  const size_t QKV_B = (size_t)16 * 1152 * NPF * 2;   // 115.6 MB
  ushort* qkv = (ushort*)(ws + 1310720);
  ushort* xw  = (ushort*)(ws + 1310720 + QKV_B);      // 38.5 MB (ws >= 155.5 MB proven)

  hipLaunchKernelGGL(k_bias, dim3(113), dim3(256), 0, stream, cpb, bias);
  hipLaunchKernelGGL(k_rmap, dim3(13), dim3(256), 0, stream, rmap);
  hipLaunchKernelGGL(k_wcvt, dim3(288), dim3(256), 0, stream, wqkv, wproj, wqb, wpb);
  hipLaunchKernelGGL(k_xw, dim3(196), dim3(256), 0, stream, x, rmap, xw);
  hipLaunchKernelGGL(k_qkv_pm, dim3(1872), dim3(256), 0, stream, xw, wqb, qkv);
  hipLaunchKernelGGL(k_attn_pm, dim3(NWIN * HEADS), dim3(64), 0, stream, qkv, bias);
  hipLaunchKernelGGL(k_proj_pm, dim3(1200), dim3(256), 0, stream, qkv, wpb, out);
}

// Round 20
// 308.961 us; speedup vs baseline: 1.3543x; 1.0106x over previous
//
#include <hip/hip_runtime.h>
#include <hip/hip_bf16.h>
#include <math.h>

#define DIM   384
#define HEADS 12
#define HD    32
#define WIN   7
#define NPIX  49
#define IMG   56
#define NPF   3136
#define NWIN  1024

typedef __attribute__((ext_vector_type(8))) short short8;
typedef __attribute__((ext_vector_type(4))) float f32x4;
typedef __attribute__((ext_vector_type(4))) float f4;
typedef __attribute__((ext_vector_type(4))) unsigned short us4;
typedef __attribute__((ext_vector_type(8))) unsigned short us8;
#define MFMA __builtin_amdgcn_mfma_f32_16x16x32_bf16

// barrier that does NOT drain vmcnt: LDS hazards covered by lgkmcnt(0),
// global loads stay in flight across it (counted vmcnt at their use site).
#define SOFT_BARRIER()                                         \
  do {                                                         \
    asm volatile("s_waitcnt lgkmcnt(0)" ::: "memory");         \
    __builtin_amdgcn_s_barrier();                              \
  } while (0)

__device__ inline ushort tob(float f) {
  unsigned u; __builtin_memcpy(&u, &f, 4);
  u += 0x7fffu + ((u >> 16) & 1u);
  return (ushort)(u >> 16);
}

// ---------------- bias table ----------------
__global__ void k_bias(const float* __restrict__ cpb, float* __restrict__ bias) {
  int idx = blockIdx.x * 256 + threadIdx.x;
  if (idx >= HEADS * NPIX * NPIX) return;
  int m = idx % NPIX;
  int n = (idx / NPIX) % NPIX;
  int h = idx / (NPIX * NPIX);
  int sy = (n / WIN - m / WIN) + (WIN - 1);
  int sx = (n % WIN - m % WIN) + (WIN - 1);
  const double inv_log_beta = 1.0 / log(1.3);
  double fy = (sy == 0 ? 0.0 : log1p((double)sy) * inv_log_beta) + 6.0;
  double fx = (sx == 0 ? 0.0 : log1p((double)sx) * inv_log_beta) + 6.0;
  fy = fmin(12.0, fmax(0.0, fy));
  fx = fmin(12.0, fmax(0.0, fx));
  int ridx = (int)(fy * 13.0 + fx);
  bias[idx] = cpb[ridx * HEADS + h];
}

__global__ void k_rmap(int* __restrict__ rmap) {
  int p = blockIdx.x * 256 + threadIdx.x;
  if (p < NPF) {
    int wb = p / NPIX, n = p - (p / NPIX) * NPIX;
    int gy = wb >> 3, gx = wb & 7;
    int wy = n / WIN, wx = n - (n / WIN) * WIN;
    rmap[p] = ((gy * WIN + wy + 4) % IMG) * IMG + (gx * WIN + wx + 4) % IMG;
  }
}

// ---------------- weights -> bf16 (once) ----------------
__global__ void k_wcvt(const float* __restrict__ wqkv, const float* __restrict__ wproj,
                       ushort* __restrict__ wqb, ushort* __restrict__ wpb) {
  int i = blockIdx.x * 256 + threadIdx.x;
  const int nq = 1152 * DIM / 8;
  const int np = DIM * DIM / 8;
  if (i < nq) {
    f4 a = *(const f4*)&wqkv[i * 8];
    f4 b = *(const f4*)&wqkv[i * 8 + 4];
    us8 u; u[0]=tob(a[0]);u[1]=tob(a[1]);u[2]=tob(a[2]);u[3]=tob(a[3]);
    u[4]=tob(b[0]);u[5]=tob(b[1]);u[6]=tob(b[2]);u[7]=tob(b[3]);
    *(us8*)&wqb[i * 8] = u;
  } else if (i < nq + np) {
    int j = i - nq;
    f4 a = *(const f4*)&wproj[j * 8];
    f4 b = *(const f4*)&wproj[j * 8 + 4];
    us8 u; u[0]=tob(a[0]);u[1]=tob(a[1]);u[2]=tob(a[2]);u[3]=tob(a[3]);
    u[4]=tob(b[0]);u[5]=tob(b[1]);u[6]=tob(b[2]);u[7]=tob(b[3]);
    *(us8*)&wpb[j * 8] = u;
  }
}

// ---------------- x -> xw[b][p'][c] bf16, window-ordered, roll folded -------
__global__ __launch_bounds__(256) void k_xw(const float* __restrict__ x,
                                            const int* __restrict__ rmap,
                                            ushort* __restrict__ xw) {
  int gid = blockIdx.x * 256 + threadIdx.x;
  int b = gid / NPF, p = gid - (gid / NPF) * NPF;
  int sp = rmap[p];
  const float* xs = x + (size_t)b * DIM * NPF + sp;
  ushort* xd = xw + ((size_t)b * NPF + p) * DIM;
  for (int c0 = 0; c0 < DIM; c0 += 8) {
    us8 u;
#pragma unroll
    for (int i = 0; i < 8; ++i) u[i] = tob(xs[(size_t)(c0 + i) * NPF]);
    *(us8*)&xd[c0] = u;
  }
}

// ---------------- QKV GEMM: 2-ahead staging + soft barriers -----------------
__global__ __launch_bounds__(256) void k_qkv_pm(const ushort* __restrict__ xw,
                                                const ushort* __restrict__ wqb,
                                                ushort* __restrict__ qkv) {
  __shared__ __align__(16) ushort sA[2][128 * 40];
  __shared__ __align__(16) ushort sB[2][256 * 40];
  int t   = threadIdx.x;
  int bid = blockIdx.x;
  int swz = (bid & 7) * 234 + (bid >> 3);   // 1872 = 8*234, bijective
  int o0  = (swz % 9) * 128;
  int pbt = swz / 9;
  int p0  = (pbt % 13) * 256;
  int b   = pbt / 13;

  int lane = t & 63, w = t >> 6;
  int wm = w >> 1, wn = w & 1;
  int l15 = lane & 15, l4 = lane >> 4;

  int arow = t & 127, ash = (t >> 7) * 16;
  const ushort* apt = wqb + (size_t)(o0 + arow) * DIM + ash;
  int brow = t;
  int prow = p0 + brow; if (prow >= NPF) prow = NPF - 1;
  const ushort* bpt = xw + ((size_t)b * NPF + prow) * DIM;

  struct Stage { us8 a0, a1, b0, b1, b2, b3; };
  Stage st0, st1;

#define QLOAD(S, K0)                                    \
  do {                                                  \
    (S).a0 = *(const us8*)&apt[(K0)];                   \
    (S).a1 = *(const us8*)&apt[(K0) + 8];               \
    (S).b0 = *(const us8*)&bpt[(K0)];                   \
    (S).b1 = *(const us8*)&bpt[(K0) + 8];               \
    (S).b2 = *(const us8*)&bpt[(K0) + 16];              \
    (S).b3 = *(const us8*)&bpt[(K0) + 24];              \
  } while (0)
#define QWRITE(S, BUF)                                  \
  do {                                                  \
    *(us8*)&sA[(BUF)][arow * 40 + ash]     = (S).a0;    \
    *(us8*)&sA[(BUF)][arow * 40 + ash + 8] = (S).a1;    \
    *(us8*)&sB[(BUF)][brow * 40]      = (S).b0;         \
    *(us8*)&sB[(BUF)][brow * 40 + 8]  = (S).b1;         \
    *(us8*)&sB[(BUF)][brow * 40 + 16] = (S).b2;         \
    *(us8*)&sB[(BUF)][brow * 40 + 24] = (S).b3;         \
  } while (0)

  f32x4 acc[4][8] = {};

  QLOAD(st0, 0);        // G0
  QWRITE(st0, 0);
  QLOAD(st1, 32);       // G1

#pragma unroll
  for (int ks = 0; ks < 12; ++ks) {
    SOFT_BARRIER();
    // issue G(ks+2) into the freed set (whose content is already in LDS)
    if (ks < 10) {
      if ((ks & 1) == 0) QLOAD(st0, (ks + 2) * 32);
      else               QLOAD(st1, (ks + 2) * 32);
    }
    int cur = ks & 1;
    short8 af[4], bfr[8];
#pragma unroll
    for (int mi = 0; mi < 4; ++mi)
      af[mi] = *(const short8*)&sA[cur][(wm * 64 + mi * 16 + l15) * 40 + l4 * 8];
#pragma unroll
    for (int ni = 0; ni < 8; ++ni)
      bfr[ni] = *(const short8*)&sB[cur][(wn * 128 + ni * 16 + l15) * 40 + l4 * 8];
#pragma unroll
    for (int mi = 0; mi < 4; ++mi)
#pragma unroll
      for (int ni = 0; ni < 8; ++ni)
        acc[mi][ni] = MFMA(af[mi], bfr[ni], acc[mi][ni], 0, 0, 0);
    // write G(ks+1) (loaded a full iteration ago; counted vmcnt auto-inserted)
    if (ks < 11) {
      if ((ks & 1) == 0) QWRITE(st1, 1);
      else               QWRITE(st0, 0);
    }
  }
#undef QLOAD
#undef QWRITE

#pragma unroll
  for (int mi = 0; mi < 4; ++mi)
#pragma unroll
    for (int ni = 0; ni < 8; ++ni) {
      int p = p0 + wn * 128 + ni * 16 + l15;
      if (p < NPF) {
        us4 u;
#pragma unroll
        for (int r = 0; r < 4; ++r) u[r] = tob(acc[mi][ni][r]);
        *(us4*)&qkv[((size_t)b * NPF + p) * 1152 + o0 + wm * 64 + mi * 16 + (l4 << 2)] = u;
      }
    }
}

// ---------------- attention (r12 verbatim) ----------------
__global__ __launch_bounds__(64) void k_attn_pm(ushort* __restrict__ qkv,
                                                const float* __restrict__ bias) {
  __shared__ __align__(16) ushort smem[8992];
  ushort* sq  = smem;          // [64][40]
  ushort* skt = smem + 2560;   // [64][40]
  ushort* svt = smem + 5120;   // [32][72]
  ushort* stg = smem + 7424;   // [49][32]
  ushort* pa  = smem;          // [64][72] overlays sq/skt

  int t = threadIdx.x;
  int bid = blockIdx.x;
  int swz = (bid & 7) * 1536 + (bid >> 3);   // 12288 = 8*1536
  int h = swz % HEADS, wb = swz / HEADS;
  int b = wb >> 6;
  int w49 = (wb & 63) * NPIX;
  ushort* qrow = qkv + ((size_t)b * NPF + w49) * 1152 + h * HD;

  for (int idx = t; idx < 32 * 23; idx += 64) {
    int d = idx / 23, mm = 49 + (idx - (idx / 23) * 23);
    svt[d * 72 + mm] = 0;
  }
  for (int idx = t; idx < NPIX * 4; idx += 64) {
    int n = idx >> 2, s = (idx & 3) * 8;
    *(us8*)&sq [n * 40 + s] = *(const us8*)&qrow[(size_t)n * 1152 + s];
    *(us8*)&skt[n * 40 + s] = *(const us8*)&qrow[(size_t)n * 1152 + DIM + s];
    *(us8*)&stg[n * 32 + s] = *(const us8*)&qrow[(size_t)n * 1152 + 2 * DIM + s];
  }
  __syncthreads();
  for (int idx = t; idx < HD * NPIX; idx += 64) {
    int d = idx / NPIX, m = idx - d * NPIX;
    svt[d * 72 + m] = stg[m * 32 + d];
  }
  __syncthreads();

  int l15 = t & 15, l4 = t >> 4;
  f32x4 acc[4][4] = {};
  {
    short8 af[4], bfr[4];
#pragma unroll
    for (int mi = 0; mi < 4; ++mi) af[mi]  = *(const short8*)&sq [(mi * 16 + l15) * 40 + l4 * 8];
#pragma unroll
    for (int ni = 0; ni < 4; ++ni) bfr[ni] = *(const short8*)&skt[(ni * 16 + l15) * 40 + l4 * 8];
#pragma unroll
    for (int mi = 0; mi < 4; ++mi)
#pragma unroll
      for (int ni = 0; ni < 4; ++ni)
        acc[mi][ni] = MFMA(af[mi], bfr[ni], acc[mi][ni], 0, 0, 0);
  }

  const float scale = 0.17677669529663687f;
  const float* bh = bias + h * NPIX * NPIX;
  float mx[16], sm[16];
#pragma unroll
  for (int mi = 0; mi < 4; ++mi)
#pragma unroll
    for (int r = 0; r < 4; ++r) {
      int n = mi * 16 + (l4 << 2) + r;
      float vmax = -3e38f;
#pragma unroll
      for (int ni = 0; ni < 4; ++ni) {
        int m = ni * 16 + l15;
        float s = (m < NPIX)
                    ? acc[mi][ni][r] * scale + ((n < NPIX) ? bh[n * NPIX + m] : 0.f)
                    : -3e38f;
        acc[mi][ni][r] = s;
        vmax = fmaxf(vmax, s);
      }
      mx[mi * 4 + r] = vmax;
    }
#pragma unroll
  for (int i = 1; i < 16; i <<= 1)
#pragma unroll
    for (int j = 0; j < 16; ++j) mx[j] = fmaxf(mx[j], __shfl_xor(mx[j], i));
#pragma unroll
  for (int mi = 0; mi < 4; ++mi)
#pragma unroll
    for (int r = 0; r < 4; ++r) {
      float s = 0.f;
#pragma unroll
      for (int ni = 0; ni < 4; ++ni) {
        float e = expf(acc[mi][ni][r] - mx[mi * 4 + r]);
        acc[mi][ni][r] = e;
        s += e;
      }
      sm[mi * 4 + r] = s;
    }
#pragma unroll
  for (int i = 1; i < 16; i <<= 1)
#pragma unroll
    for (int j = 0; j < 16; ++j) sm[j] += __shfl_xor(sm[j], i);

  __syncthreads();
#pragma unroll
  for (int mi = 0; mi < 4; ++mi)
#pragma unroll
    for (int r = 0; r < 4; ++r) {
      float ri = 1.f / sm[mi * 4 + r];
      int n = mi * 16 + (l4 << 2) + r;
#pragma unroll
      for (int ni = 0; ni < 4; ++ni)
        pa[n * 72 + ni * 16 + l15] = tob(acc[mi][ni][r] * ri);
    }
  __syncthreads();

  f32x4 yac[4][2] = {};
#pragma unroll
  for (int ks = 0; ks < 2; ++ks) {
    short8 pf[4], vf[2];
#pragma unroll
    for (int mi = 0; mi < 4; ++mi) pf[mi] = *(const short8*)&pa [(mi * 16 + l15) * 72 + ks * 32 + l4 * 8];
#pragma unroll
    for (int nd = 0; nd < 2; ++nd) vf[nd] = *(const short8*)&svt[(nd * 16 + l15) * 72 + ks * 32 + l4 * 8];
#pragma unroll
    for (int mi = 0; mi < 4; ++mi)
#pragma unroll
      for (int nd = 0; nd < 2; ++nd)
        yac[mi][nd] = MFMA(pf[mi], vf[nd], yac[mi][nd], 0, 0, 0);
  }
#pragma unroll
  for (int mi = 0; mi < 4; ++mi)
#pragma unroll
    for (int nd = 0; nd < 2; ++nd) {
      int nb = mi * 16 + (l4 << 2);
      int d = nd * 16 + l15;
#pragma unroll
      for (int r = 0; r < 4; ++r)
        if (nb + r < NPIX) qrow[(size_t)(nb + r) * 1152 + d] = tob(yac[mi][nd][r]);
    }
}

// ---------------- proj GEMM: 128x128 + 2-ahead staging + soft barriers ------
__global__ __launch_bounds__(256) void k_proj_pm(const ushort* __restrict__ qkv,
                                                 const ushort* __restrict__ wpb,
                                                 float* __restrict__ out) {
  __shared__ __align__(16) ushort sA[2][128 * 40];
  __shared__ __align__(16) ushort sB[2][128 * 40];
  __shared__ int srm[128];
  int t   = threadIdx.x;
  int bid = blockIdx.x;
  int swz = (bid & 7) * 150 + (bid >> 3);   // 1200 = 8*150
  int o0  = (swz % 3) * 128;
  int pb  = swz / 3;
  int p0  = (pb % 25) * 128;
  int b   = pb / 25;
  if (t < 128) {
    int pg = p0 + t;
    if (pg >= NPF) pg = 0;
    int si = (pg / IMG + 53) % IMG, sj = (pg % IMG + 53) % IMG;
    srm[t] = ((si / WIN) * 8 + sj / WIN) * NPIX + (si % WIN) * WIN + (sj % WIN);
  }
  __syncthreads();

  int lane = t & 63, w = t >> 6;
  int wm = w >> 1, wn = w & 1;
  int l15 = lane & 15, l4 = lane >> 4;

  int row = t & 127, sh = (t >> 7) * 16;
  const ushort* apt = wpb + (size_t)(o0 + row) * DIM;
  const ushort* bpt = qkv + ((size_t)b * NPF + srm[row]) * 1152;

  struct Stage { us8 a0, a1, b0, b1; };
  Stage st0, st1;

#define PLOAD(S, K0)                                    \
  do {                                                  \
    (S).a0 = *(const us8*)&apt[(K0) + sh];              \
    (S).a1 = *(const us8*)&apt[(K0) + sh + 8];          \
    (S).b0 = *(const us8*)&bpt[(K0) + sh];              \
    (S).b1 = *(const us8*)&bpt[(K0) + sh + 8];          \
  } while (0)
#define PWRITE(S, BUF)                                  \
  do {                                                  \
    *(us8*)&sA[(BUF)][row * 40 + sh]     = (S).a0;      \
    *(us8*)&sA[(BUF)][row * 40 + sh + 8] = (S).a1;      \
    *(us8*)&sB[(BUF)][row * 40 + sh]     = (S).b0;      \
    *(us8*)&sB[(BUF)][row * 40 + sh + 8] = (S).b1;      \
  } while (0)

  f32x4 acc[4][4] = {};

  PLOAD(st0, 0);
  PWRITE(st0, 0);
  PLOAD(st1, 32);

#pragma unroll
  for (int ks = 0; ks < 12; ++ks) {
    SOFT_BARRIER();
    if (ks < 10) {
      if ((ks & 1) == 0) PLOAD(st0, (ks + 2) * 32);
      else               PLOAD(st1, (ks + 2) * 32);
    }
    int cur = ks & 1;
    short8 af[4], bfr[4];
#pragma unroll
    for (int mi = 0; mi < 4; ++mi)
      af[mi] = *(const short8*)&sA[cur][(wm * 64 + mi * 16 + l15) * 40 + l4 * 8];
#pragma unroll
    for (int ni = 0; ni < 4; ++ni)
      bfr[ni] = *(const short8*)&sB[cur][(wn * 64 + ni * 16 + l15) * 40 + l4 * 8];
#pragma unroll
    for (int mi = 0; mi < 4; ++mi)
#pragma unroll
      for (int ni = 0; ni < 4; ++ni)
        acc[mi][ni] = MFMA(af[mi], bfr[ni], acc[mi][ni], 0, 0, 0);
    if (ks < 11) {
      if ((ks & 1) == 0) PWRITE(st1, 1);
      else               PWRITE(st0, 0);
    }
  }
#undef PLOAD
#undef PWRITE

  for (int mi = 0; mi < 4; ++mi)
    for (int ni = 0; ni < 4; ++ni)
      for (int r = 0; r < 4; ++r) {
        int o = o0 + wm * 64 + mi * 16 + (l4 << 2) + r;
        int p = p0 + wn * 64 + ni * 16 + l15;
        if (p < NPF)
          out[((size_t)b * DIM + o) * NPF + p] = acc[mi][ni][r];
      }
}

extern "C" void kernel_launch(void* const* d_in, const int* in_sizes, int n_in,
                              void* d_out, int out_size, void* d_ws, size_t ws_size,
                              hipStream_t stream) {
  const float* x     = (const float*)d_in[0];
  const float* wqkv  = (const float*)d_in[1];
  const float* wproj = (const float*)d_in[2];
  const float* cpb   = (const float*)d_in[3];
  float* out = (float*)d_out;

  char* ws = (char*)d_ws;
  float* bias = (float*)ws;                       // 115248 B
  int*   rmap = (int*)(ws + 115712);              // -> 131072
  ushort* wqb = (ushort*)(ws + 131072);           // 884736 B
  ushort* wpb = (ushort*)(ws + 1015808);          // 294912 B -> 1310720
  const size_t QKV_B = (size_t)16 * 1152 * NPF * 2;   // 115.6 MB
  ushort* qkv = (ushort*)(ws + 1310720);
  ushort* xw  = (ushort*)(ws + 1310720 + QKV_B);      // 38.5 MB (ws >= 155.5 MB proven)

  hipLaunchKernelGGL(k_bias, dim3(113), dim3(256), 0, stream, cpb, bias);
  hipLaunchKernelGGL(k_rmap, dim3(13), dim3(256), 0, stream, rmap);
  hipLaunchKernelGGL(k_wcvt, dim3(288), dim3(256), 0, stream, wqkv, wproj, wqb, wpb);
  hipLaunchKernelGGL(k_xw, dim3(196), dim3(256), 0, stream, x, rmap, xw);
  hipLaunchKernelGGL(k_qkv_pm, dim3(1872), dim3(256), 0, stream, xw, wqb, qkv);
  hipLaunchKernelGGL(k_attn_pm, dim3(NWIN * HEADS), dim3(64), 0, stream, qkv, bias);
  hipLaunchKernelGGL(k_proj_pm, dim3(1200), dim3(256), 0, stream, qkv, wpb, out);
}